// Round 1
// baseline (125.713 us; speedup 1.0000x reference)
//
#include <hip/hip_runtime.h>

// Problem constants (match reference)
#define NB 32768   // batch rows
#define NF 256     // features
#define NH 8       // hidden dim
#define ROWS_PER_BLOCK 16

// One thread per feature. Each thread keeps its feature's full MLP params
// (8 + 8 + 64 + 8 + 8 = 96 floats) in registers and loops over rows.
// Per row: coalesced x load, 80 FMAs, coalesced w store, wave-reduce + atomicAdd
// for the per-row sum.
__global__ __launch_bounds__(256) void NAM_49314814493074_kernel(
    const float* __restrict__ input,   // [B, F]
    const float* __restrict__ W1,      // [F, 8]
    const float* __restrict__ b1,      // [F, 8]
    const float* __restrict__ W2,      // [F, 8, 8]
    const float* __restrict__ b2,      // [F, 8]
    const float* __restrict__ W3,      // [F, 8]
    float* __restrict__ out_sum,       // [B]   (pre-zeroed)
    float* __restrict__ out_w)         // [B, F]
{
    const int f = threadIdx.x;                  // feature index 0..255
    const int row0 = blockIdx.x * ROWS_PER_BLOCK;

    // ---- load per-feature params into registers (explicit float4) ----
    float w1[NH], bb1[NH], bb2[NH], w3[NH];
    float w2[NH][NH];
    {
        const float4* p1 = reinterpret_cast<const float4*>(W1 + (size_t)f * NH);
        const float4* pb1 = reinterpret_cast<const float4*>(b1 + (size_t)f * NH);
        const float4* pb2 = reinterpret_cast<const float4*>(b2 + (size_t)f * NH);
        const float4* p3 = reinterpret_cast<const float4*>(W3 + (size_t)f * NH);
        float4 a, b;
        a = p1[0]; b = p1[1];
        w1[0]=a.x; w1[1]=a.y; w1[2]=a.z; w1[3]=a.w; w1[4]=b.x; w1[5]=b.y; w1[6]=b.z; w1[7]=b.w;
        a = pb1[0]; b = pb1[1];
        bb1[0]=a.x; bb1[1]=a.y; bb1[2]=a.z; bb1[3]=a.w; bb1[4]=b.x; bb1[5]=b.y; bb1[6]=b.z; bb1[7]=b.w;
        a = pb2[0]; b = pb2[1];
        bb2[0]=a.x; bb2[1]=a.y; bb2[2]=a.z; bb2[3]=a.w; bb2[4]=b.x; bb2[5]=b.y; bb2[6]=b.z; bb2[7]=b.w;
        a = p3[0]; b = p3[1];
        w3[0]=a.x; w3[1]=a.y; w3[2]=a.z; w3[3]=a.w; w3[4]=b.x; w3[5]=b.y; w3[6]=b.z; w3[7]=b.w;

        const float4* p2 = reinterpret_cast<const float4*>(W2 + (size_t)f * NH * NH);
        #pragma unroll
        for (int h = 0; h < NH; ++h) {
            float4 c0 = p2[h * 2 + 0];
            float4 c1 = p2[h * 2 + 1];
            w2[h][0]=c0.x; w2[h][1]=c0.y; w2[h][2]=c0.z; w2[h][3]=c0.w;
            w2[h][4]=c1.x; w2[h][5]=c1.y; w2[h][6]=c1.z; w2[h][7]=c1.w;
        }
    }

    // ---- main loop over this block's rows ----
    #pragma unroll 2
    for (int r = 0; r < ROWS_PER_BLOCK; ++r) {
        const int brow = row0 + r;
        const float x = input[(size_t)brow * NF + f];

        // h1 = relu(x * W1 + b1)
        float h1[NH];
        #pragma unroll
        for (int h = 0; h < NH; ++h)
            h1[h] = fmaxf(fmaf(x, w1[h], bb1[h]), 0.0f);

        // h2 = relu(h1 @ W2 + b2)  (8x8 matvec, 8 independent accumulators)
        float acc[NH];
        #pragma unroll
        for (int k = 0; k < NH; ++k) acc[k] = bb2[k];
        #pragma unroll
        for (int h = 0; h < NH; ++h) {
            #pragma unroll
            for (int k = 0; k < NH; ++k)
                acc[k] = fmaf(h1[h], w2[h][k], acc[k]);
        }

        // w = h2 . W3
        float s = 0.0f;
        #pragma unroll
        for (int k = 0; k < NH; ++k)
            s = fmaf(fmaxf(acc[k], 0.0f), w3[k], s);

        out_w[(size_t)brow * NF + f] = s;

        // per-row sum over all 256 features: wave butterfly + 1 atomic per wave
        float ws = s;
        #pragma unroll
        for (int off = 32; off > 0; off >>= 1)
            ws += __shfl_xor(ws, off, 64);
        if ((threadIdx.x & 63) == 0)
            atomicAdd(&out_sum[brow], ws);
    }
}

extern "C" void kernel_launch(void* const* d_in, const int* in_sizes, int n_in,
                              void* d_out, int out_size, void* d_ws, size_t ws_size,
                              hipStream_t stream) {
    const float* input = (const float*)d_in[0];
    const float* W1    = (const float*)d_in[1];
    const float* b1    = (const float*)d_in[2];
    const float* W2    = (const float*)d_in[3];
    const float* b2    = (const float*)d_in[4];
    const float* W3    = (const float*)d_in[5];

    float* out = (float*)d_out;          // [B] sums, then [B,F] w
    float* out_sum = out;
    float* out_w   = out + NB;

    // zero the atomic-accumulated region (harness poisons d_out with 0xAA)
    hipMemsetAsync(out_sum, 0, NB * sizeof(float), stream);

    dim3 grid(NB / ROWS_PER_BLOCK);      // 2048 blocks
    dim3 block(NF);                      // 256 threads = 1 per feature
    NAM_49314814493074_kernel<<<grid, block, 0, stream>>>(
        input, W1, b1, W2, b2, W3, out_sum, out_w);
}

// Round 2
// 112.847 us; speedup vs baseline: 1.1140x; 1.1140x over previous
//
#include <hip/hip_runtime.h>

// Problem constants (match reference)
#define NB 32768   // batch rows
#define NF 256     // features
#define NH 8       // hidden dim
#define ROWS_PER_BLOCK 32

// One thread per feature. Each thread keeps its feature's full MLP params
// (8 + 8 + 64 + 8 + 8 = 96 floats) in registers (launch_bounds 256,2 gives the
// allocator room: 256 VGPR cap) and loops over 32 rows. Per row: coalesced x
// load, ~96 VALU ops, coalesced w store, stash s in LDS. One barrier at the
// end, then each wave reduces 8 rows from LDS (conflict-free) and writes the
// per-row sums directly — no atomics, no per-row shuffle chains.
__global__ __launch_bounds__(256, 2) void NAM_49314814493074_kernel(
    const float* __restrict__ input,   // [B, F]
    const float* __restrict__ W1,      // [F, 8]
    const float* __restrict__ b1,      // [F, 8]
    const float* __restrict__ W2,      // [F, 8, 8]
    const float* __restrict__ b2,      // [F, 8]
    const float* __restrict__ W3,      // [F, 8]
    float* __restrict__ out_sum,       // [B]
    float* __restrict__ out_w)         // [B, F]
{
    __shared__ float sred[ROWS_PER_BLOCK][NF];   // 32 KB

    const int f = threadIdx.x;                  // feature index 0..255
    const int row0 = blockIdx.x * ROWS_PER_BLOCK;

    // ---- load per-feature params into registers (explicit float4) ----
    float w1[NH], bb1[NH], bb2[NH], w3[NH];
    float w2[NH][NH];
    {
        const float4* p1  = reinterpret_cast<const float4*>(W1 + (size_t)f * NH);
        const float4* pb1 = reinterpret_cast<const float4*>(b1 + (size_t)f * NH);
        const float4* pb2 = reinterpret_cast<const float4*>(b2 + (size_t)f * NH);
        const float4* p3  = reinterpret_cast<const float4*>(W3 + (size_t)f * NH);
        float4 a, b;
        a = p1[0]; b = p1[1];
        w1[0]=a.x; w1[1]=a.y; w1[2]=a.z; w1[3]=a.w; w1[4]=b.x; w1[5]=b.y; w1[6]=b.z; w1[7]=b.w;
        a = pb1[0]; b = pb1[1];
        bb1[0]=a.x; bb1[1]=a.y; bb1[2]=a.z; bb1[3]=a.w; bb1[4]=b.x; bb1[5]=b.y; bb1[6]=b.z; bb1[7]=b.w;
        a = pb2[0]; b = pb2[1];
        bb2[0]=a.x; bb2[1]=a.y; bb2[2]=a.z; bb2[3]=a.w; bb2[4]=b.x; bb2[5]=b.y; bb2[6]=b.z; bb2[7]=b.w;
        a = p3[0]; b = p3[1];
        w3[0]=a.x; w3[1]=a.y; w3[2]=a.z; w3[3]=a.w; w3[4]=b.x; w3[5]=b.y; w3[6]=b.z; w3[7]=b.w;

        const float4* p2 = reinterpret_cast<const float4*>(W2 + (size_t)f * NH * NH);
        #pragma unroll
        for (int h = 0; h < NH; ++h) {
            float4 c0 = p2[h * 2 + 0];
            float4 c1 = p2[h * 2 + 1];
            w2[h][0]=c0.x; w2[h][1]=c0.y; w2[h][2]=c0.z; w2[h][3]=c0.w;
            w2[h][4]=c1.x; w2[h][5]=c1.y; w2[h][6]=c1.z; w2[h][7]=c1.w;
        }
    }

    // ---- main loop over this block's rows ----
    const float* xin = input + (size_t)row0 * NF + f;
    float* wout = out_w + (size_t)row0 * NF + f;

    #pragma unroll 2
    for (int r = 0; r < ROWS_PER_BLOCK; ++r) {
        const float x = xin[(size_t)r * NF];

        // h1 = relu(x * W1 + b1)
        float h1[NH];
        #pragma unroll
        for (int h = 0; h < NH; ++h)
            h1[h] = fmaxf(fmaf(x, w1[h], bb1[h]), 0.0f);

        // h2 = relu(h1 @ W2 + b2)  (8x8 matvec, 8 independent accumulators)
        float acc[NH];
        #pragma unroll
        for (int k = 0; k < NH; ++k) acc[k] = bb2[k];
        #pragma unroll
        for (int h = 0; h < NH; ++h) {
            #pragma unroll
            for (int k = 0; k < NH; ++k)
                acc[k] = fmaf(h1[h], w2[h][k], acc[k]);
        }

        // w = relu(h2) . W3
        float s = 0.0f;
        #pragma unroll
        for (int k = 0; k < NH; ++k)
            s = fmaf(fmaxf(acc[k], 0.0f), w3[k], s);

        wout[(size_t)r * NF] = s;
        sred[r][f] = s;
    }

    __syncthreads();

    // ---- per-row sums: wave w reduces rows [8w, 8w+8) ----
    const int wave = threadIdx.x >> 6;
    const int lane = threadIdx.x & 63;
    #pragma unroll
    for (int rr = 0; rr < ROWS_PER_BLOCK / 4; ++rr) {
        const int r = wave * (ROWS_PER_BLOCK / 4) + rr;
        float v = sred[r][lane] + sred[r][lane + 64]
                + sred[r][lane + 128] + sred[r][lane + 192];
        #pragma unroll
        for (int off = 32; off > 0; off >>= 1)
            v += __shfl_xor(v, off, 64);
        if (lane == 0)
            out_sum[row0 + r] = v;
    }
}

extern "C" void kernel_launch(void* const* d_in, const int* in_sizes, int n_in,
                              void* d_out, int out_size, void* d_ws, size_t ws_size,
                              hipStream_t stream) {
    const float* input = (const float*)d_in[0];
    const float* W1    = (const float*)d_in[1];
    const float* b1    = (const float*)d_in[2];
    const float* W2    = (const float*)d_in[3];
    const float* b2    = (const float*)d_in[4];
    const float* W3    = (const float*)d_in[5];

    float* out = (float*)d_out;          // [B] sums, then [B,F] w
    float* out_sum = out;
    float* out_w   = out + NB;

    dim3 grid(NB / ROWS_PER_BLOCK);      // 1024 blocks
    dim3 block(NF);                      // 256 threads = 1 per feature
    NAM_49314814493074_kernel<<<grid, block, 0, stream>>>(
        input, W1, b1, W2, b2, W3, out_sum, out_w);
}

// Round 3
// 106.313 us; speedup vs baseline: 1.1825x; 1.0615x over previous
//
#include <hip/hip_runtime.h>

// Problem constants (match reference)
#define NB 32768   // batch rows
#define NF 256     // features
#define NH 8       // hidden dim
#define ROWS_PER_BLOCK 32

// One thread per feature; 96 MLP params live in registers for the whole
// kernel. All 32 row inputs are prefetched into registers in one load burst
// (decouples HBM/L2 latency from the compute chain — only row 0 ever waits),
// then 32 rows are computed fully unrolled. Row sums via one block barrier +
// per-wave LDS b128 reads + 6-step shuffle butterfly; no atomics.
__global__ __launch_bounds__(256, 2) void NAM_49314814493074_kernel(
    const float* __restrict__ input,   // [B, F]
    const float* __restrict__ W1,      // [F, 8]
    const float* __restrict__ b1,      // [F, 8]
    const float* __restrict__ W2,      // [F, 8, 8]
    const float* __restrict__ b2,      // [F, 8]
    const float* __restrict__ W3,      // [F, 8]
    float* __restrict__ out_sum,       // [B]
    float* __restrict__ out_w)         // [B, F]
{
    __shared__ float sred[ROWS_PER_BLOCK][NF];   // 32 KB

    const int f = threadIdx.x;                  // feature index 0..255
    const int row0 = blockIdx.x * ROWS_PER_BLOCK;

    const float* xin = input + (size_t)row0 * NF + f;
    float* wout = out_w + (size_t)row0 * NF + f;

    // ---- prefetch all 32 x values into registers (32 loads in flight) ----
    float xv[ROWS_PER_BLOCK];
    #pragma unroll
    for (int r = 0; r < ROWS_PER_BLOCK; ++r)
        xv[r] = xin[(size_t)r * NF];

    // ---- load per-feature params into registers (explicit float4) ----
    float w1[NH], bb1[NH], bb2[NH], w3[NH];
    float w2[NH][NH];
    {
        const float4* p1  = reinterpret_cast<const float4*>(W1 + (size_t)f * NH);
        const float4* pb1 = reinterpret_cast<const float4*>(b1 + (size_t)f * NH);
        const float4* pb2 = reinterpret_cast<const float4*>(b2 + (size_t)f * NH);
        const float4* p3  = reinterpret_cast<const float4*>(W3 + (size_t)f * NH);
        float4 a, b;
        a = p1[0]; b = p1[1];
        w1[0]=a.x; w1[1]=a.y; w1[2]=a.z; w1[3]=a.w; w1[4]=b.x; w1[5]=b.y; w1[6]=b.z; w1[7]=b.w;
        a = pb1[0]; b = pb1[1];
        bb1[0]=a.x; bb1[1]=a.y; bb1[2]=a.z; bb1[3]=a.w; bb1[4]=b.x; bb1[5]=b.y; bb1[6]=b.z; bb1[7]=b.w;
        a = pb2[0]; b = pb2[1];
        bb2[0]=a.x; bb2[1]=a.y; bb2[2]=a.z; bb2[3]=a.w; bb2[4]=b.x; bb2[5]=b.y; bb2[6]=b.z; bb2[7]=b.w;
        a = p3[0]; b = p3[1];
        w3[0]=a.x; w3[1]=a.y; w3[2]=a.z; w3[3]=a.w; w3[4]=b.x; w3[5]=b.y; w3[6]=b.z; w3[7]=b.w;

        const float4* p2 = reinterpret_cast<const float4*>(W2 + (size_t)f * NH * NH);
        #pragma unroll
        for (int h = 0; h < NH; ++h) {
            float4 c0 = p2[h * 2 + 0];
            float4 c1 = p2[h * 2 + 1];
            w2[h][0]=c0.x; w2[h][1]=c0.y; w2[h][2]=c0.z; w2[h][3]=c0.w;
            w2[h][4]=c1.x; w2[h][5]=c1.y; w2[h][6]=c1.z; w2[h][7]=c1.w;
        }
    }

    // ---- compute all rows, fully unrolled (xv[r] must be static-indexed) ----
    #pragma unroll
    for (int r = 0; r < ROWS_PER_BLOCK; ++r) {
        const float x = xv[r];

        // h1 = relu(x * W1 + b1)
        float h1[NH];
        #pragma unroll
        for (int h = 0; h < NH; ++h)
            h1[h] = fmaxf(fmaf(x, w1[h], bb1[h]), 0.0f);

        // h2 = relu(h1 @ W2 + b2)  (8x8 matvec, 8 independent accumulators)
        float acc[NH];
        #pragma unroll
        for (int k = 0; k < NH; ++k) acc[k] = bb2[k];
        #pragma unroll
        for (int h = 0; h < NH; ++h) {
            #pragma unroll
            for (int k = 0; k < NH; ++k)
                acc[k] = fmaf(h1[h], w2[h][k], acc[k]);
        }

        // w = relu(h2) . W3
        float s = 0.0f;
        #pragma unroll
        for (int k = 0; k < NH; ++k)
            s = fmaf(fmaxf(acc[k], 0.0f), w3[k], s);

        wout[(size_t)r * NF] = s;
        sred[r][f] = s;
    }

    __syncthreads();

    // ---- per-row sums: wave w reduces rows [8w, 8w+8) ----
    const int wave = threadIdx.x >> 6;
    const int lane = threadIdx.x & 63;
    #pragma unroll
    for (int rr = 0; rr < ROWS_PER_BLOCK / 4; ++rr) {
        const int r = wave * (ROWS_PER_BLOCK / 4) + rr;
        const float4 q = reinterpret_cast<const float4*>(&sred[r][0])[lane];
        float v = q.x + q.y + q.z + q.w;
        #pragma unroll
        for (int off = 32; off > 0; off >>= 1)
            v += __shfl_xor(v, off, 64);
        if (lane == 0)
            out_sum[row0 + r] = v;
    }
}

extern "C" void kernel_launch(void* const* d_in, const int* in_sizes, int n_in,
                              void* d_out, int out_size, void* d_ws, size_t ws_size,
                              hipStream_t stream) {
    const float* input = (const float*)d_in[0];
    const float* W1    = (const float*)d_in[1];
    const float* b1    = (const float*)d_in[2];
    const float* W2    = (const float*)d_in[3];
    const float* b2    = (const float*)d_in[4];
    const float* W3    = (const float*)d_in[5];

    float* out = (float*)d_out;          // [B] sums, then [B,F] w
    float* out_sum = out;
    float* out_w   = out + NB;

    dim3 grid(NB / ROWS_PER_BLOCK);      // 1024 blocks
    dim3 block(NF);                      // 256 threads = 1 per feature
    NAM_49314814493074_kernel<<<grid, block, 0, stream>>>(
        input, W1, b1, W2, b2, W3, out_sum, out_w);
}